// Round 1
// baseline (284.579 us; speedup 1.0000x reference)
//
#include <hip/hip_runtime.h>

typedef _Float16 f16;
typedef _Float16 f16x8 __attribute__((ext_vector_type(8)));
typedef float f32x4 __attribute__((ext_vector_type(4)));

#define MFMA16(a, b, c) __builtin_amdgcn_mfma_f32_16x16x32_f16(a, b, c, 0, 0, 0)

// ---------------- kernel 0: convert weights to fp16 ----------------
// Wall[384][256]: rows 0-127 theta_w, 128-255 phi_w, 256-383 g_w
// Wepi[256][128]: W_w
__global__ __launch_bounds__(256) void wcvt_k(
    const float* __restrict__ tw, const float* __restrict__ pw,
    const float* __restrict__ gw, const float* __restrict__ ww,
    f16* __restrict__ Wall, f16* __restrict__ Wepi) {
  int i = blockIdx.x * 256 + threadIdx.x;
  if (i < 384 * 256) {
    int c = i >> 8, cp = i & 255;
    float v = (c < 128) ? tw[c * 256 + cp]
            : (c < 256) ? pw[(c - 128) * 256 + cp]
                        : gw[(c - 256) * 256 + cp];
    Wall[i] = (f16)v;
  }
  int j = i - 384 * 256;
  if (j >= 0 && j < 256 * 128) Wepi[j] = (f16)ww[j];
}

// ---------------- kernel 1: transpose x [B,256,4096] fp32 -> xT [B,4096,256] fp16 ----
__global__ __launch_bounds__(256) void xpose_k(const float* __restrict__ x,
                                               f16* __restrict__ xT) {
  __shared__ f16 t[64 * 65];
  int bx = blockIdx.x;
  int b = bx >> 8, rem = bx & 255;
  int c0 = (rem >> 6) * 64, n0 = (rem & 63) * 64;
  const float* xb = x + ((size_t)b * 256 + c0) * 4096 + n0;
#pragma unroll
  for (int rep = 0; rep < 16; ++rep) {
    int idx = rep * 256 + threadIdx.x;
    int i = idx >> 6, j = idx & 63;  // i: c-local, j: n-local
    t[j * 65 + i] = (f16)xb[(size_t)i * 4096 + j];
  }
  __syncthreads();
  f16* o = xT + ((size_t)b * 4096 + n0) * 256 + c0;
#pragma unroll
  for (int rep = 0; rep < 16; ++rep) {
    int idx = rep * 256 + threadIdx.x;
    int j = idx >> 6, i = idx & 63;
    o[(size_t)j * 256 + i] = t[j * 65 + i];
  }
}

// ---------------- kernel 2: projection GEMM ----------------
// out[n][c] = sum_k xT[n][k] * Wall[c][k] + bias[c]
// c in [0,128) -> Q[n][c]; [128,256) -> K[n][c-128]; [256,384) -> Vt[c-256][n]
__global__ __launch_bounds__(256) void proj_k(
    const f16* __restrict__ xT, const f16* __restrict__ Wall,
    const float* __restrict__ tb, const float* __restrict__ pb,
    const float* __restrict__ gb, f16* __restrict__ Q, f16* __restrict__ K,
    f16* __restrict__ Vt) {
  __shared__ f16 vs[128 * 65];
  int b = blockIdx.x >> 6, nt = blockIdx.x & 63;
  int nbase = nt * 64;
  int w = threadIdx.x >> 6, lane = threadIdx.x & 63;
  int lr = lane & 15, lhi = lane >> 4;
  int nrow = nbase + w * 16 + lr;
  const f16x8* xr = (const f16x8*)(xT + ((size_t)b * 4096 + nrow) * 256);
  f16x8 a[8];
#pragma unroll
  for (int ks = 0; ks < 8; ++ks) a[ks] = xr[ks * 4 + lhi];
  f32x4 acc[24];
#pragma unroll
  for (int ct = 0; ct < 24; ++ct) {
    acc[ct] = {0.f, 0.f, 0.f, 0.f};
    const f16x8* wr = (const f16x8*)(Wall + (size_t)(ct * 16 + lr) * 256);
#pragma unroll
    for (int ks = 0; ks < 8; ++ks) acc[ct] = MFMA16(a[ks], wr[ks * 4 + lhi], acc[ct]);
  }
  int nloc = w * 16 + lhi * 4;
#pragma unroll
  for (int ct = 0; ct < 24; ++ct) {
    int c = ct * 16 + lr;
    float bias = (c < 128) ? tb[c] : (c < 256) ? pb[c - 128] : gb[c - 256];
#pragma unroll
    for (int r = 0; r < 4; ++r) {
      float v = acc[ct][r] + bias;
      int n = nbase + nloc + r;
      if (c < 128)
        Q[((size_t)b * 4096 + n) * 128 + c] = (f16)v;
      else if (c < 256)
        K[((size_t)b * 4096 + n) * 128 + (c - 128)] = (f16)v;
      else
        vs[(c - 256) * 65 + nloc + r] = (f16)v;
    }
  }
  __syncthreads();
  f16* vo = Vt + (size_t)b * 128 * 4096 + nbase;
  for (int rep = 0; rep < 32; ++rep) {
    int idx = rep * 256 + threadIdx.x;
    int c = idx >> 6, j = idx & 63;
    vo[(size_t)c * 4096 + j] = vs[c * 65 + j];
  }
}

// ---------------- kernel 3: flash attention ----------------
// Q,K: [B,4096,128] f16. Vt: [B,128,4096] f16. Y: [B,4096,128] f16 = softmax(QK^T) V
__global__ __launch_bounds__(256) void attn_k(const f16* __restrict__ Q,
                                              const f16* __restrict__ K,
                                              const f16* __restrict__ Vt,
                                              f16* __restrict__ Y) {
  __shared__ f16 Ks[64 * 136];
  __shared__ f16 Vs[128 * 72];
  __shared__ f16 Pl[4 * 16 * 72];
  int b = blockIdx.x >> 6, qt = blockIdx.x & 63;
  int qbase = qt * 64;
  int w = threadIdx.x >> 6, lane = threadIdx.x & 63;
  int lr = lane & 15, lhi = lane >> 4;
  const f16x8* qr = (const f16x8*)(Q + ((size_t)b * 4096 + qbase + w * 16 + lr) * 128);
  f16x8 aq[4];
#pragma unroll
  for (int ks = 0; ks < 4; ++ks) aq[ks] = qr[ks * 4 + lhi];
  f32x4 yacc[8];
#pragma unroll
  for (int ct = 0; ct < 8; ++ct) yacc[ct] = {0.f, 0.f, 0.f, 0.f};
  float m[4], l[4];
#pragma unroll
  for (int r = 0; r < 4; ++r) { m[r] = -1e30f; l[r] = 0.f; }
  int si = threadIdx.x >> 2, sq = threadIdx.x & 3;  // K staging: row si, 32-col blk sq
  int vc = threadIdx.x >> 1, vh = threadIdx.x & 1;  // V staging: row vc, 32-col blk vh
  const f16* Kbase = K + (size_t)b * 4096 * 128;
  const f16* Vbase = Vt + (size_t)b * 128 * 4096;
  f16* Plw = &Pl[w * 16 * 72];

  for (int t = 0; t < 64; ++t) {
    int kv = t * 64;
    __syncthreads();
    {
      const f16x8* src = (const f16x8*)(Kbase + (size_t)(kv + si) * 128 + sq * 32);
      f16x8* dst = (f16x8*)(&Ks[si * 136 + sq * 32]);
#pragma unroll
      for (int u = 0; u < 4; ++u) dst[u] = src[u];
      const f16x8* vsrc = (const f16x8*)(Vbase + (size_t)vc * 4096 + kv + vh * 32);
      f16x8* vdst = (f16x8*)(&Vs[vc * 72 + vh * 32]);
#pragma unroll
      for (int u = 0; u < 4; ++u) vdst[u] = vsrc[u];
    }
    __syncthreads();
    // S = Q K^T for this wave's 16 rows x 64 kv cols
    f32x4 s[4];
#pragma unroll
    for (int jt = 0; jt < 4; ++jt) {
      s[jt] = {0.f, 0.f, 0.f, 0.f};
#pragma unroll
      for (int ks = 0; ks < 4; ++ks) {
        f16x8 bk = *(const f16x8*)(&Ks[(jt * 16 + lr) * 136 + ks * 32 + lhi * 8]);
        s[jt] = MFMA16(aq[ks], bk, s[jt]);
      }
    }
    // online softmax (rows = lhi*4 + r, spread over 16 lanes lr)
    float mnew[4], sc[4];
#pragma unroll
    for (int r = 0; r < 4; ++r) {
      float v = fmaxf(fmaxf(s[0][r], s[1][r]), fmaxf(s[2][r], s[3][r]));
#pragma unroll
      for (int off = 1; off < 16; off <<= 1) v = fmaxf(v, __shfl_xor(v, off));
      mnew[r] = fmaxf(m[r], v);
      sc[r] = __expf(m[r] - mnew[r]);
      m[r] = mnew[r];
    }
    float rs[4] = {0.f, 0.f, 0.f, 0.f};
#pragma unroll
    for (int jt = 0; jt < 4; ++jt)
#pragma unroll
      for (int r = 0; r < 4; ++r) {
        float p = __expf(s[jt][r] - mnew[r]);
        s[jt][r] = p;
        rs[r] += p;
      }
#pragma unroll
    for (int r = 0; r < 4; ++r) {
      float v = rs[r];
#pragma unroll
      for (int off = 1; off < 16; off <<= 1) v += __shfl_xor(v, off);
      l[r] = l[r] * sc[r] + v;
    }
#pragma unroll
    for (int ct = 0; ct < 8; ++ct)
#pragma unroll
      for (int r = 0; r < 4; ++r) yacc[ct][r] *= sc[r];
    // P -> per-wave LDS (re-fragment C-layout -> A-layout)
#pragma unroll
    for (int jt = 0; jt < 4; ++jt)
#pragma unroll
      for (int r = 0; r < 4; ++r)
        Plw[(lhi * 4 + r) * 72 + jt * 16 + lr] = (f16)s[jt][r];
    asm volatile("s_waitcnt lgkmcnt(0)" ::: "memory");
    f16x8 pa[2];
#pragma unroll
    for (int k2 = 0; k2 < 2; ++k2)
      pa[k2] = *(const f16x8*)(&Plw[lr * 72 + k2 * 32 + lhi * 8]);
#pragma unroll
    for (int ct = 0; ct < 8; ++ct) {
#pragma unroll
      for (int k2 = 0; k2 < 2; ++k2) {
        f16x8 bv = *(const f16x8*)(&Vs[(ct * 16 + lr) * 72 + k2 * 32 + lhi * 8]);
        yacc[ct] = MFMA16(pa[k2], bv, yacc[ct]);
      }
    }
  }
  f16* yo = Y + ((size_t)b * 4096 + qbase + w * 16) * 128;
#pragma unroll
  for (int r = 0; r < 4; ++r) {
    float inv = 1.0f / l[r];
#pragma unroll
    for (int ct = 0; ct < 8; ++ct)
      yo[(size_t)(lhi * 4 + r) * 128 + ct * 16 + lr] = (f16)(yacc[ct][r] * inv);
  }
}

// ---------------- kernel 4: epilogue GEMM + bias + residual ----------------
// out[b][o][n] = x[b][o][n] + Wb[o] + sum_c Wepi[o][c] * Y[b][n][c]
__global__ __launch_bounds__(256) void epi_k(const f16* __restrict__ Y,
                                             const f16* __restrict__ Wepi,
                                             const float* __restrict__ Wb,
                                             const float* __restrict__ x,
                                             float* __restrict__ out) {
  int b = blockIdx.x >> 6, nt = blockIdx.x & 63;
  int nbase = nt * 64;
  int w = threadIdx.x >> 6, lane = threadIdx.x & 63;
  int lr = lane & 15, lhi = lane >> 4;
  f16x8 by[4][4];
#pragma unroll
  for (int n4 = 0; n4 < 4; ++n4) {
    const f16x8* yr = (const f16x8*)(Y + ((size_t)b * 4096 + nbase + n4 * 16 + lr) * 128);
#pragma unroll
    for (int ks = 0; ks < 4; ++ks) by[n4][ks] = yr[ks * 4 + lhi];
  }
#pragma unroll
  for (int ot = 0; ot < 4; ++ot) {
    int o0 = w * 64 + ot * 16;
    const f16x8* wr = (const f16x8*)(Wepi + (size_t)(o0 + lr) * 128);
    f16x8 a[4];
#pragma unroll
    for (int ks = 0; ks < 4; ++ks) a[ks] = wr[ks * 4 + lhi];
#pragma unroll
    for (int n4 = 0; n4 < 4; ++n4) {
      f32x4 acc = {0.f, 0.f, 0.f, 0.f};
#pragma unroll
      for (int ks = 0; ks < 4; ++ks) acc = MFMA16(a[ks], by[n4][ks], acc);
#pragma unroll
      for (int r = 0; r < 4; ++r) {
        int o = o0 + lhi * 4 + r;
        int n = nbase + n4 * 16 + lr;
        size_t idx = ((size_t)b * 256 + o) * 4096 + n;
        out[idx] = x[idx] + Wb[o] + acc[r];
      }
    }
  }
}

extern "C" void kernel_launch(void* const* d_in, const int* in_sizes, int n_in,
                              void* d_out, int out_size, void* d_ws, size_t ws_size,
                              hipStream_t stream) {
  const float* x       = (const float*)d_in[0];
  const float* g_w     = (const float*)d_in[1];
  const float* g_b     = (const float*)d_in[2];
  const float* theta_w = (const float*)d_in[3];
  const float* theta_b = (const float*)d_in[4];
  const float* phi_w   = (const float*)d_in[5];
  const float* phi_b   = (const float*)d_in[6];
  const float* W_w     = (const float*)d_in[7];
  const float* W_b     = (const float*)d_in[8];
  float* out = (float*)d_out;

  f16* xT   = (f16*)d_ws;                       // [8,4096,256]
  f16* Q    = xT + (size_t)8 * 4096 * 256;      // [8,4096,128]
  f16* Kk   = Q + (size_t)8 * 4096 * 128;       // [8,4096,128]
  f16* Vt   = Kk + (size_t)8 * 4096 * 128;      // [8,128,4096]
  f16* Wall = Vt + (size_t)8 * 4096 * 128;      // [384,256]
  f16* Wepi = Wall + 384 * 256;                 // [256,128]
  f16* Y    = xT;                                // reuse xT region

  wcvt_k<<<512, 256, 0, stream>>>(theta_w, phi_w, g_w, W_w, Wall, Wepi);
  xpose_k<<<2048, 256, 0, stream>>>(x, xT);
  proj_k<<<512, 256, 0, stream>>>(xT, Wall, theta_b, phi_b, g_b, Q, Kk, Vt);
  attn_k<<<512, 256, 0, stream>>>(Q, Kk, Vt, Y);
  epi_k<<<512, 256, 0, stream>>>(Y, Wepi, W_b, x, out);
}

// Round 2
// 232.873 us; speedup vs baseline: 1.2220x; 1.2220x over previous
//
#include <hip/hip_runtime.h>

typedef _Float16 f16;
typedef _Float16 f16x4 __attribute__((ext_vector_type(4)));
typedef _Float16 f16x8 __attribute__((ext_vector_type(8)));
typedef float f32x4 __attribute__((ext_vector_type(4)));
typedef float f32x16 __attribute__((ext_vector_type(16)));

#define MFMA16(a, b, c) __builtin_amdgcn_mfma_f32_16x16x32_f16(a, b, c, 0, 0, 0)
#define MFMA32(a, b, c) __builtin_amdgcn_mfma_f32_32x32x16_f16(a, b, c, 0, 0, 0)

// ---------------- kernel 0: convert weights to fp16 ----------------
__global__ __launch_bounds__(256) void wcvt_k(
    const float* __restrict__ tw, const float* __restrict__ pw,
    const float* __restrict__ gw, const float* __restrict__ ww,
    f16* __restrict__ Wall, f16* __restrict__ Wepi) {
  int i = blockIdx.x * 256 + threadIdx.x;
  if (i < 384 * 256) {
    int c = i >> 8, cp = i & 255;
    float v = (c < 128) ? tw[c * 256 + cp]
            : (c < 256) ? pw[(c - 128) * 256 + cp]
                        : gw[(c - 256) * 256 + cp];
    Wall[i] = (f16)v;
  }
  int j = i - 384 * 256;
  if (j >= 0 && j < 256 * 128) Wepi[j] = (f16)ww[j];
}

// ---------------- kernel 1: transpose x [B,256,4096] fp32 -> xT [B,4096,256] fp16 ----
__global__ __launch_bounds__(256) void xpose_k(const float* __restrict__ x,
                                               f16* __restrict__ xT) {
  __shared__ f16 t[64 * 65];
  int bx = blockIdx.x;
  int b = bx >> 8, rem = bx & 255;
  int c0 = (rem >> 6) * 64, n0 = (rem & 63) * 64;
  const float* xb = x + ((size_t)b * 256 + c0) * 4096 + n0;
#pragma unroll
  for (int rep = 0; rep < 16; ++rep) {
    int idx = rep * 256 + threadIdx.x;
    int i = idx >> 6, j = idx & 63;
    t[j * 65 + i] = (f16)xb[(size_t)i * 4096 + j];
  }
  __syncthreads();
  f16* o = xT + ((size_t)b * 4096 + n0) * 256 + c0;
#pragma unroll
  for (int rep = 0; rep < 16; ++rep) {
    int idx = rep * 256 + threadIdx.x;
    int j = idx >> 6, i = idx & 63;
    o[(size_t)j * 256 + i] = t[j * 65 + i];
  }
}

// ---------------- kernel 2: projection GEMM ----------------
__global__ __launch_bounds__(256) void proj_k(
    const f16* __restrict__ xT, const f16* __restrict__ Wall,
    const float* __restrict__ tb, const float* __restrict__ pb,
    const float* __restrict__ gb, f16* __restrict__ Q, f16* __restrict__ K,
    f16* __restrict__ Vt) {
  __shared__ f16 vs[128 * 65];
  int b = blockIdx.x >> 6, nt = blockIdx.x & 63;
  int nbase = nt * 64;
  int w = threadIdx.x >> 6, lane = threadIdx.x & 63;
  int lr = lane & 15, lhi = lane >> 4;
  int nrow = nbase + w * 16 + lr;
  const f16x8* xr = (const f16x8*)(xT + ((size_t)b * 4096 + nrow) * 256);
  f16x8 a[8];
#pragma unroll
  for (int ks = 0; ks < 8; ++ks) a[ks] = xr[ks * 4 + lhi];
  f32x4 acc[24];
#pragma unroll
  for (int ct = 0; ct < 24; ++ct) {
    acc[ct] = {0.f, 0.f, 0.f, 0.f};
    const f16x8* wr = (const f16x8*)(Wall + (size_t)(ct * 16 + lr) * 256);
#pragma unroll
    for (int ks = 0; ks < 8; ++ks) acc[ct] = MFMA16(a[ks], wr[ks * 4 + lhi], acc[ct]);
  }
  int nloc = w * 16 + lhi * 4;
#pragma unroll
  for (int ct = 0; ct < 24; ++ct) {
    int c = ct * 16 + lr;
    float bias = (c < 128) ? tb[c] : (c < 256) ? pb[c - 128] : gb[c - 256];
#pragma unroll
    for (int r = 0; r < 4; ++r) {
      float v = acc[ct][r] + bias;
      int n = nbase + nloc + r;
      if (c < 128)
        Q[((size_t)b * 4096 + n) * 128 + c] = (f16)v;
      else if (c < 256)
        K[((size_t)b * 4096 + n) * 128 + (c - 128)] = (f16)v;
      else
        vs[(c - 256) * 65 + nloc + r] = (f16)v;
    }
  }
  __syncthreads();
  f16* vo = Vt + (size_t)b * 128 * 4096 + nbase;
  for (int rep = 0; rep < 32; ++rep) {
    int idx = rep * 256 + threadIdx.x;
    int c = idx >> 6, j = idx & 63;
    vo[(size_t)c * 4096 + j] = vs[c * 65 + j];
  }
}

// ---------------- kernel 3: flash attention (32x32 swapped-QK^T) ----------------
// Q,K: [B,4096,128] f16. Vt: [B,128,4096] f16. Y: [B,4096,128] f16.
// Block: 4 waves x 32 q-rows = 128 q-rows. Grid: 8 * 32 = 256.
// S^T = mfma(A=K, B=Q): lane owns q = lane&31; kv = (reg&3)+8*(reg>>2)+4*hi.
// Y^T = mfma(A=Vt, B=P): lane holds Y^T[d][q] for its q.
__global__ __launch_bounds__(256, 1) void attn_k(const f16* __restrict__ Q,
                                                 const f16* __restrict__ K,
                                                 const f16* __restrict__ Vt,
                                                 f16* __restrict__ Y) {
  __shared__ f16 Ks[2][64 * 128];
  __shared__ f16 Vs[2][128 * 64];
  __shared__ f16 Pl[4][32 * 64];
  const float L = 1.44269504f;
  int b = blockIdx.x >> 5, qt = blockIdx.x & 31;
  int qbase = qt * 128;
  int tid = threadIdx.x;
  int w = tid >> 6, lane = tid & 63;
  int col = lane & 31, hi = lane >> 5;
  int psw = (col & 7) << 4;

  // Q B-fragments (held for the whole kernel)
  const f16* Qr = Q + ((size_t)b * 4096 + qbase + w * 32 + col) * 128;
  f16x8 bq[8];
#pragma unroll
  for (int ks = 0; ks < 8; ++ks) bq[ks] = *(const f16x8*)(Qr + ks * 16 + hi * 8);

  f32x16 yacc[4];
#pragma unroll
  for (int dt = 0; dt < 4; ++dt)
#pragma unroll
    for (int r = 0; r < 16; ++r) yacc[dt][r] = 0.f;
  float m = -1e30f, l = 0.f;
  float nmL = 1e30f * L;  // -m * log2e

  const f16* Kbase = K + (size_t)b * 4096 * 128;
  const f16* Vbase = Vt + (size_t)b * 128 * 4096;
  char* PlwB = (char*)&Pl[w][0];

  // staging maps
  int krow = tid >> 4, kcolb = (tid & 15) * 16;  // K: row r*16+krow, 16B col kcolb
  int vrow = tid >> 1, vcolb0 = (tid & 1) * 64;  // V: row vrow, 64B half vcolb0

  // prologue: stage tile 0 into buffer 0
  {
    const f16* Kt = Kbase;  // kv0 = 0, tile is contiguous 64*128 f16
    f16x8 kr[4], vr[4];
#pragma unroll
    for (int r = 0; r < 4; ++r) kr[r] = *(const f16x8*)(Kt + (r * 256 + tid) * 8);
#pragma unroll
    for (int u = 0; u < 4; ++u)
      vr[u] = *(const f16x8*)(Vbase + (size_t)vrow * 4096 + (vcolb0 >> 1) + u * 8);
#pragma unroll
    for (int r = 0; r < 4; ++r) {
      int row = r * 16 + krow;
      *(f16x8*)((char*)Ks[0] + row * 256 + (kcolb ^ ((row & 7) << 4))) = kr[r];
    }
#pragma unroll
    for (int u = 0; u < 4; ++u)
      *(f16x8*)((char*)Vs[0] + vrow * 128 + ((vcolb0 + u * 16) ^ ((vrow & 7) << 4))) = vr[u];
  }

  for (int t = 0; t < 64; ++t) {
    int cur = t & 1, nxt = cur ^ 1;
    // T14: issue next tile's global loads before compute
    f16x8 kr[4], vr[4];
    bool pf = (t + 1 < 64);
    if (pf) {
      int kv0 = (t + 1) * 64;
      const f16* Kt = Kbase + (size_t)kv0 * 128;
#pragma unroll
      for (int r = 0; r < 4; ++r) kr[r] = *(const f16x8*)(Kt + (r * 256 + tid) * 8);
#pragma unroll
      for (int u = 0; u < 4; ++u)
        vr[u] = *(const f16x8*)(Vbase + (size_t)vrow * 4096 + kv0 + (vcolb0 >> 1) + u * 8);
    }
    __syncthreads();  // buf[cur] writes visible; everyone done reading buf[nxt]

    // ---- S^T = K . Q^T  (A = K rows, B = Q) ----
    f32x16 s2[2];
#pragma unroll
    for (int t2 = 0; t2 < 2; ++t2) {
#pragma unroll
      for (int r = 0; r < 16; ++r) s2[t2][r] = 0.f;
      int row = t2 * 32 + col;
      const char* kb = (const char*)Ks[cur] + row * 256;
#pragma unroll
      for (int ks = 0; ks < 8; ++ks) {
        f16x8 ak = *(const f16x8*)(kb + ((ks * 32 + hi * 16) ^ psw));
        s2[t2] = MFMA32(ak, bq[ks], s2[t2]);
      }
    }

    // ---- per-lane online softmax for q = col ----
    float v[16];
#pragma unroll
    for (int r = 0; r < 16; ++r) v[r] = fmaxf(s2[0][r], s2[1][r]);
#pragma unroll
    for (int st = 8; st > 0; st >>= 1)
#pragma unroll
      for (int i = 0; i < 16; ++i)
        if (i < st) v[i] = fmaxf(v[i], v[i + st]);
    float pm = v[0];
    pm = fmaxf(pm, __shfl_xor(pm, 32));
    if (pm > m + 8.f) {  // T13 defer-max
      float sc = __expf(m - pm);
      m = pm;
      nmL = -m * L;
      l *= sc;
#pragma unroll
      for (int dt = 0; dt < 4; ++dt)
#pragma unroll
        for (int r = 0; r < 16; ++r) yacc[dt][r] *= sc;
    }
    float p[2][16];
#pragma unroll
    for (int t2 = 0; t2 < 2; ++t2)
#pragma unroll
      for (int r = 0; r < 16; ++r) p[t2][r] = exp2f(fmaf(s2[t2][r], L, nmL));
    // tree sum
    float sv[16];
#pragma unroll
    for (int r = 0; r < 16; ++r) sv[r] = p[0][r] + p[1][r];
#pragma unroll
    for (int st = 8; st > 0; st >>= 1)
#pragma unroll
      for (int i = 0; i < 16; ++i)
        if (i < st) sv[i] += sv[i + st];
    float rs = sv[0];
    rs += __shfl_xor(rs, 32);
    l += rs;
    // P -> per-warp LDS (vectorized b64, swizzled)
#pragma unroll
    for (int t2 = 0; t2 < 2; ++t2)
#pragma unroll
      for (int a = 0; a < 4; ++a) {
        f16x4 pv = {(f16)p[t2][4 * a], (f16)p[t2][4 * a + 1], (f16)p[t2][4 * a + 2],
                    (f16)p[t2][4 * a + 3]};
        *(f16x4*)(PlwB + col * 128 + ((t2 * 64 + a * 16 + hi * 8) ^ psw)) = pv;
      }
    asm volatile("s_waitcnt lgkmcnt(0)" ::: "memory");

    // ---- Y^T += V^T . P^T  (A = Vt rows, B = P) ----
#pragma unroll
    for (int kstep = 0; kstep < 4; ++kstep) {
      f16x8 pb = *(const f16x8*)(PlwB + col * 128 + ((kstep * 32 + hi * 16) ^ psw));
#pragma unroll
      for (int dt = 0; dt < 4; ++dt) {
        int row = dt * 32 + col;
        f16x8 av =
            *(const f16x8*)((const char*)Vs[cur] + row * 128 + ((kstep * 32 + hi * 16) ^ psw));
        yacc[dt] = MFMA32(av, pb, yacc[dt]);
      }
    }

    // write staged next tile (safe: all waves past this iter's barrier)
    if (pf) {
#pragma unroll
      for (int r = 0; r < 4; ++r) {
        int row = r * 16 + krow;
        *(f16x8*)((char*)Ks[nxt] + row * 256 + (kcolb ^ ((row & 7) << 4))) = kr[r];
      }
#pragma unroll
      for (int u = 0; u < 4; ++u)
        *(f16x8*)((char*)Vs[nxt] + vrow * 128 + ((vcolb0 + u * 16) ^ ((vrow & 7) << 4))) = vr[u];
    }
  }

  // epilogue: normalize and store Y[n=q][c=d]
  float inv = 1.0f / l;
  f16* yo = Y + ((size_t)b * 4096 + qbase + w * 32 + col) * 128;
#pragma unroll
  for (int dt = 0; dt < 4; ++dt)
#pragma unroll
    for (int a = 0; a < 4; ++a) {
      f16x4 ov = {(f16)(yacc[dt][4 * a] * inv), (f16)(yacc[dt][4 * a + 1] * inv),
                  (f16)(yacc[dt][4 * a + 2] * inv), (f16)(yacc[dt][4 * a + 3] * inv)};
      *(f16x4*)(yo + dt * 32 + a * 8 + hi * 4) = ov;
    }
}

// ---------------- kernel 4: epilogue GEMM + bias + residual ----------------
__global__ __launch_bounds__(256) void epi_k(const f16* __restrict__ Y,
                                             const f16* __restrict__ Wepi,
                                             const float* __restrict__ Wb,
                                             const float* __restrict__ x,
                                             float* __restrict__ out) {
  int b = blockIdx.x >> 6, nt = blockIdx.x & 63;
  int nbase = nt * 64;
  int w = threadIdx.x >> 6, lane = threadIdx.x & 63;
  int lr = lane & 15, lhi = lane >> 4;
  f16x8 by[4][4];
#pragma unroll
  for (int n4 = 0; n4 < 4; ++n4) {
    const f16x8* yr = (const f16x8*)(Y + ((size_t)b * 4096 + nbase + n4 * 16 + lr) * 128);
#pragma unroll
    for (int ks = 0; ks < 4; ++ks) by[n4][ks] = yr[ks * 4 + lhi];
  }
#pragma unroll
  for (int ot = 0; ot < 4; ++ot) {
    int o0 = w * 64 + ot * 16;
    const f16x8* wr = (const f16x8*)(Wepi + (size_t)(o0 + lr) * 128);
    f16x8 a[4];
#pragma unroll
    for (int ks = 0; ks < 4; ++ks) a[ks] = wr[ks * 4 + lhi];
#pragma unroll
    for (int n4 = 0; n4 < 4; ++n4) {
      f32x4 acc = {0.f, 0.f, 0.f, 0.f};
#pragma unroll
      for (int ks = 0; ks < 4; ++ks) acc = MFMA16(a[ks], by[n4][ks], acc);
#pragma unroll
      for (int r = 0; r < 4; ++r) {
        int o = o0 + lhi * 4 + r;
        int n = nbase + n4 * 16 + lr;
        size_t idx = ((size_t)b * 256 + o) * 4096 + n;
        out[idx] = x[idx] + Wb[o] + acc[r];
      }
    }
  }
}

extern "C" void kernel_launch(void* const* d_in, const int* in_sizes, int n_in,
                              void* d_out, int out_size, void* d_ws, size_t ws_size,
                              hipStream_t stream) {
  const float* x       = (const float*)d_in[0];
  const float* g_w     = (const float*)d_in[1];
  const float* g_b     = (const float*)d_in[2];
  const float* theta_w = (const float*)d_in[3];
  const float* theta_b = (const float*)d_in[4];
  const float* phi_w   = (const float*)d_in[5];
  const float* phi_b   = (const float*)d_in[6];
  const float* W_w     = (const float*)d_in[7];
  const float* W_b     = (const float*)d_in[8];
  float* out = (float*)d_out;

  f16* xT   = (f16*)d_ws;                       // [8,4096,256]
  f16* Q    = xT + (size_t)8 * 4096 * 256;      // [8,4096,128]
  f16* Kk   = Q + (size_t)8 * 4096 * 128;       // [8,4096,128]
  f16* Vt   = Kk + (size_t)8 * 4096 * 128;      // [8,128,4096]
  f16* Wall = Vt + (size_t)8 * 4096 * 128;      // [384,256]
  f16* Wepi = Wall + 384 * 256;                 // [256,128]
  f16* Y    = xT;                               // reuse xT region

  wcvt_k<<<512, 256, 0, stream>>>(theta_w, phi_w, g_w, W_w, Wall, Wepi);
  xpose_k<<<2048, 256, 0, stream>>>(x, xT);
  proj_k<<<512, 256, 0, stream>>>(xT, Wall, theta_b, phi_b, g_b, Q, Kk, Vt);
  attn_k<<<256, 256, 0, stream>>>(Q, Kk, Vt, Y);
  epi_k<<<512, 256, 0, stream>>>(Y, Wepi, W_b, x, out);
}

// Round 4
// 195.236 us; speedup vs baseline: 1.4576x; 1.1928x over previous
//
#include <hip/hip_runtime.h>

typedef _Float16 f16;
typedef _Float16 f16x2 __attribute__((ext_vector_type(2)));
typedef _Float16 f16x4 __attribute__((ext_vector_type(4)));
typedef _Float16 f16x8 __attribute__((ext_vector_type(8)));
typedef float f32x4 __attribute__((ext_vector_type(4)));
typedef float f32x16 __attribute__((ext_vector_type(16)));

#define MFMA16(a, b, c) __builtin_amdgcn_mfma_f32_16x16x32_f16(a, b, c, 0, 0, 0)
#define MFMA32(a, b, c) __builtin_amdgcn_mfma_f32_32x32x16_f16(a, b, c, 0, 0, 0)

__device__ __forceinline__ int swzr(int row) { return ((row & 7) << 4) ^ ((row & 8) << 2); }

// ---------------- kernel 0: convert weights to fp16 ----------------
__global__ __launch_bounds__(256) void wcvt_k(
    const float* __restrict__ tw, const float* __restrict__ pw,
    const float* __restrict__ gw, const float* __restrict__ ww,
    f16* __restrict__ Wall, f16* __restrict__ Wepi) {
  int i = blockIdx.x * 256 + threadIdx.x;
  if (i < 384 * 256) {
    int c = i >> 8, cp = i & 255;
    float v = (c < 128) ? tw[c * 256 + cp]
            : (c < 256) ? pw[(c - 128) * 256 + cp]
                        : gw[(c - 256) * 256 + cp];
    Wall[i] = (f16)v;
  }
  int j = i - 384 * 256;
  if (j >= 0 && j < 256 * 128) Wepi[j] = (f16)ww[j];
}

// ---------------- kernel 1: transpose x -> xT fp16 ----------------
__global__ __launch_bounds__(256) void xpose_k(const float* __restrict__ x,
                                               f16* __restrict__ xT) {
  __shared__ f16 t[64 * 65];
  int bx = blockIdx.x;
  int b = bx >> 8, rem = bx & 255;
  int c0 = (rem >> 6) * 64, n0 = (rem & 63) * 64;
  const float* xb = x + ((size_t)b * 256 + c0) * 4096 + n0;
#pragma unroll
  for (int rep = 0; rep < 16; ++rep) {
    int idx = rep * 256 + threadIdx.x;
    int i = idx >> 6, j = idx & 63;
    t[j * 65 + i] = (f16)xb[(size_t)i * 4096 + j];
  }
  __syncthreads();
  f16* o = xT + ((size_t)b * 4096 + n0) * 256 + c0;
#pragma unroll
  for (int rep = 0; rep < 16; ++rep) {
    int idx = rep * 256 + threadIdx.x;
    int j = idx >> 6, i = idx & 63;
    o[(size_t)j * 256 + i] = t[j * 65 + i];
  }
}

// ---------------- kernel 2: projection GEMM ----------------
__global__ __launch_bounds__(256) void proj_k(
    const f16* __restrict__ xT, const f16* __restrict__ Wall,
    const float* __restrict__ tb, const float* __restrict__ pb,
    const float* __restrict__ gb, f16* __restrict__ Q, f16* __restrict__ K,
    f16* __restrict__ Vt) {
  __shared__ f16 vs[128 * 65];
  int b = blockIdx.x >> 6, nt = blockIdx.x & 63;
  int nbase = nt * 64;
  int w = threadIdx.x >> 6, lane = threadIdx.x & 63;
  int lr = lane & 15, lhi = lane >> 4;
  int nrow = nbase + w * 16 + lr;
  const f16x8* xr = (const f16x8*)(xT + ((size_t)b * 4096 + nrow) * 256);
  f16x8 a[8];
#pragma unroll
  for (int ks = 0; ks < 8; ++ks) a[ks] = xr[ks * 4 + lhi];
  f32x4 acc[24];
#pragma unroll
  for (int ct = 0; ct < 24; ++ct) {
    acc[ct] = {0.f, 0.f, 0.f, 0.f};
    const f16x8* wr = (const f16x8*)(Wall + (size_t)(ct * 16 + lr) * 256);
#pragma unroll
    for (int ks = 0; ks < 8; ++ks) acc[ct] = MFMA16(a[ks], wr[ks * 4 + lhi], acc[ct]);
  }
  int nloc = w * 16 + lhi * 4;
#pragma unroll
  for (int ct = 0; ct < 24; ++ct) {
    int c = ct * 16 + lr;
    float bias = (c < 128) ? tb[c] : (c < 256) ? pb[c - 128] : gb[c - 256];
#pragma unroll
    for (int r = 0; r < 4; ++r) {
      float v = acc[ct][r] + bias;
      int n = nbase + nloc + r;
      if (c < 128)
        Q[((size_t)b * 4096 + n) * 128 + c] = (f16)v;
      else if (c < 256)
        K[((size_t)b * 4096 + n) * 128 + (c - 128)] = (f16)v;
      else
        vs[(c - 256) * 65 + nloc + r] = (f16)v;
    }
  }
  __syncthreads();
  f16* vo = Vt + (size_t)b * 128 * 4096 + nbase;
  for (int rep = 0; rep < 32; ++rep) {
    int idx = rep * 256 + threadIdx.x;
    int c = idx >> 6, j = idx & 63;
    vo[(size_t)c * 4096 + j] = vs[c * 65 + j];
  }
}

// ---------------- kernel 3: flash attention, KV-split-2, P in registers ----------------
// Grid 512: xcd-swizzled -> b = blk&7 per XCD. Each block: 128 q-rows, kv half (2048).
// Vs holds V with kv bits2<->3 swapped within 16-groups so PV B-frag = own p regs.
__global__ __launch_bounds__(256, 2) void attn_k(const f16* __restrict__ Q,
                                                 const f16* __restrict__ K,
                                                 const f16* __restrict__ Vt,
                                                 f16* __restrict__ Yp,
                                                 float2* __restrict__ ml) {
  __shared__ f16 Ks[2][64 * 128];
  __shared__ f16 Vs[2][128 * 64];
  const float L = 1.44269504f;
  int swzid = ((blockIdx.x & 7) << 6) | ((int)blockIdx.x >> 3);
  int b = swzid >> 6, rem = swzid & 63;
  int qt = rem >> 1, half = rem & 1;
  int qbase = qt * 128;
  int kvbase = half * 2048;
  int tid = threadIdx.x;
  int w = tid >> 6, lane = tid & 63;
  int col = lane & 31, hi = lane >> 5;

  const f16* Qr = Q + ((size_t)b * 4096 + qbase + w * 32 + col) * 128;
  f16x8 bq[8];
#pragma unroll
  for (int ks = 0; ks < 8; ++ks) bq[ks] = *(const f16x8*)(Qr + ks * 16 + hi * 8);

  f32x16 yacc[4];
#pragma unroll
  for (int dt = 0; dt < 4; ++dt)
#pragma unroll
    for (int r = 0; r < 16; ++r) yacc[dt][r] = 0.f;
  float m = -1e30f, l = 0.f, nmL = 1e30f;

  const f16* Kbase = K + (size_t)b * 4096 * 128;
  const f16* Vbase = Vt + (size_t)b * 128 * 4096;

  int krow = tid >> 4, kcolb = (tid & 15) * 16;  // K staging
  int vrow = tid >> 1, h2 = tid & 1;             // V staging
  int sv = swzr(vrow);

  // V write byte bases (kv bit2<->3 permute): lo4 of vr[u] -> blo, hi4 -> blo+16
  int vblo[4];
#pragma unroll
  for (int u = 0; u < 4; ++u) vblo[u] = h2 * 64 + (u & 2) * 16 + (u & 1) * 8;

  // prologue: stage tile kvbase into buffer 0
  {
    const f16* Kt = Kbase + (size_t)kvbase * 128;
    f16x8 kr[4], vr[4];
#pragma unroll
    for (int r = 0; r < 4; ++r) kr[r] = *(const f16x8*)(Kt + (r * 256 + tid) * 8);
#pragma unroll
    for (int u = 0; u < 4; ++u)
      vr[u] = *(const f16x8*)(Vbase + (size_t)vrow * 4096 + kvbase + h2 * 32 + u * 8);
#pragma unroll
    for (int r = 0; r < 4; ++r) {
      int row = r * 16 + krow;
      *(f16x8*)((char*)Ks[0] + row * 256 + (kcolb ^ swzr(row))) = kr[r];
    }
#pragma unroll
    for (int u = 0; u < 4; ++u) {
      f16x4 lo = {vr[u][0], vr[u][1], vr[u][2], vr[u][3]};
      f16x4 hi4 = {vr[u][4], vr[u][5], vr[u][6], vr[u][7]};
      *(f16x4*)((char*)Vs[0] + vrow * 128 + (vblo[u] ^ sv)) = lo;
      *(f16x4*)((char*)Vs[0] + vrow * 128 + ((vblo[u] + 16) ^ sv)) = hi4;
    }
  }

  for (int t = 0; t < 32; ++t) {
    int cur = t & 1, nxt = cur ^ 1;
    f16x8 kr[4], vr[4];
    bool pf = (t + 1 < 32);
    if (pf) {
      int kv0 = kvbase + (t + 1) * 64;
      const f16* Kt = Kbase + (size_t)kv0 * 128;
#pragma unroll
      for (int r = 0; r < 4; ++r) kr[r] = *(const f16x8*)(Kt + (r * 256 + tid) * 8);
#pragma unroll
      for (int u = 0; u < 4; ++u)
        vr[u] = *(const f16x8*)(Vbase + (size_t)vrow * 4096 + kv0 + h2 * 32 + u * 8);
    }
    __syncthreads();

    // ---- S^T = K . Q^T ----
    f32x16 s2[2];
    __builtin_amdgcn_s_setprio(1);
#pragma unroll
    for (int t2 = 0; t2 < 2; ++t2) {
#pragma unroll
      for (int r = 0; r < 16; ++r) s2[t2][r] = 0.f;
      int row = t2 * 32 + col;
      const char* kb = (const char*)Ks[cur] + row * 256;
      int sk = swzr(row);
#pragma unroll
      for (int ks = 0; ks < 8; ++ks) {
        f16x8 ak = *(const f16x8*)(kb + ((ks * 32 + hi * 16) ^ sk));
        s2[t2] = MFMA32(ak, bq[ks], s2[t2]);
      }
    }
    __builtin_amdgcn_s_setprio(0);

    // ---- per-lane online softmax for q = col ----
    float v[16];
#pragma unroll
    for (int r = 0; r < 16; ++r) v[r] = fmaxf(s2[0][r], s2[1][r]);
#pragma unroll
    for (int st = 8; st > 0; st >>= 1)
#pragma unroll
      for (int i = 0; i < 16; ++i)
        if (i < st) v[i] = fmaxf(v[i], v[i + st]);
    float pm = v[0];
    pm = fmaxf(pm, __shfl_xor(pm, 32));
    if (pm > m + 8.f) {  // T13 defer-max
      float sc = __expf(m - pm);
      m = pm;
      nmL = -m * L;
      l *= sc;
#pragma unroll
      for (int dt = 0; dt < 4; ++dt)
#pragma unroll
        for (int r = 0; r < 16; ++r) yacc[dt][r] *= sc;
    }
#pragma unroll
    for (int t2 = 0; t2 < 2; ++t2)
#pragma unroll
      for (int r = 0; r < 16; ++r) s2[t2][r] = exp2f(fmaf(s2[t2][r], L, nmL));
    float sv16[16];
#pragma unroll
    for (int r = 0; r < 16; ++r) sv16[r] = s2[0][r] + s2[1][r];
#pragma unroll
    for (int st = 8; st > 0; st >>= 1)
#pragma unroll
      for (int i = 0; i < 16; ++i)
        if (i < st) sv16[i] += sv16[i + st];
    float rs = sv16[0];
    rs += __shfl_xor(rs, 32);
    l += rs;

    // ---- P -> f16 frags, all lane-local (V columns pre-permuted) ----
    f16x8 pfr[4];
#pragma unroll
    for (int t2 = 0; t2 < 2; ++t2)
#pragma unroll
      for (int k1 = 0; k1 < 2; ++k1) {
        f16x8 f;
#pragma unroll
        for (int c = 0; c < 8; ++c) f[c] = (f16)s2[t2][8 * k1 + c];
        pfr[t2 * 2 + k1] = f;
      }

    // ---- Y^T += V . P ----
    __builtin_amdgcn_s_setprio(1);
#pragma unroll
    for (int kstep = 0; kstep < 4; ++kstep) {
#pragma unroll
      for (int dt = 0; dt < 4; ++dt) {
        int row = dt * 32 + col;
        f16x8 av = *(const f16x8*)((const char*)Vs[cur] + row * 128 +
                                   ((kstep * 32 + hi * 16) ^ swzr(row)));
        yacc[dt] = MFMA32(av, pfr[kstep], yacc[dt]);
      }
    }
    __builtin_amdgcn_s_setprio(0);

    if (pf) {
#pragma unroll
      for (int r = 0; r < 4; ++r) {
        int row = r * 16 + krow;
        *(f16x8*)((char*)Ks[nxt] + row * 256 + (kcolb ^ swzr(row))) = kr[r];
      }
#pragma unroll
      for (int u = 0; u < 4; ++u) {
        f16x4 lo = {vr[u][0], vr[u][1], vr[u][2], vr[u][3]};
        f16x4 hi4 = {vr[u][4], vr[u][5], vr[u][6], vr[u][7]};
        *(f16x4*)((char*)Vs[nxt] + vrow * 128 + (vblo[u] ^ sv)) = lo;
        *(f16x4*)((char*)Vs[nxt] + vrow * 128 + ((vblo[u] + 16) ^ sv)) = hi4;
      }
    }
  }

  // epilogue: store normalized partial + (m, l)
  size_t rowYp = (size_t)half * 32768 + (size_t)b * 4096 + qbase + w * 32 + col;
  float inv = 1.0f / l;
  f16* yo = Yp + rowYp * 128;
#pragma unroll
  for (int dt = 0; dt < 4; ++dt)
#pragma unroll
    for (int a = 0; a < 4; ++a) {
      f16x4 ov = {(f16)(yacc[dt][4 * a] * inv), (f16)(yacc[dt][4 * a + 1] * inv),
                  (f16)(yacc[dt][4 * a + 2] * inv), (f16)(yacc[dt][4 * a + 3] * inv)};
      *(f16x4*)(yo + dt * 32 + a * 8 + hi * 4) = ov;
    }
  if (hi == 0) ml[rowYp] = make_float2(m, l);
}

// ---------------- kernel 3b: flash combine of 2 kv-halves ----------------
__global__ __launch_bounds__(256) void comb_k(const f16* __restrict__ Yp,
                                              const float2* __restrict__ ml,
                                              f16* __restrict__ Y) {
  int row = blockIdx.x * 16 + (threadIdx.x >> 4);
  int e = (threadIdx.x & 15) * 8;
  float2 ml0 = ml[row], ml1 = ml[32768 + row];
  float m = fmaxf(ml0.x, ml1.x);
  float w0 = ml0.y * __expf(ml0.x - m), w1 = ml1.y * __expf(ml1.x - m);
  float inv = 1.f / (w0 + w1);
  w0 *= inv;
  w1 *= inv;
  f16x8 a = *(const f16x8*)(Yp + (size_t)row * 128 + e);
  f16x8 c = *(const f16x8*)(Yp + (size_t)(32768 + row) * 128 + e);
  f16x8 o;
#pragma unroll
  for (int i = 0; i < 8; ++i) o[i] = (f16)(w0 * (float)a[i] + w1 * (float)c[i]);
  *(f16x8*)(Y + (size_t)row * 128 + e) = o;
}

// ---------------- kernel 4: epilogue GEMM + bias + residual ----------------
__global__ __launch_bounds__(256) void epi_k(const f16* __restrict__ Y,
                                             const f16* __restrict__ Wepi,
                                             const float* __restrict__ Wb,
                                             const float* __restrict__ x,
                                             float* __restrict__ out) {
  int b = blockIdx.x >> 6, nt = blockIdx.x & 63;
  int nbase = nt * 64;
  int w = threadIdx.x >> 6, lane = threadIdx.x & 63;
  int lr = lane & 15, lhi = lane >> 4;
  f16x8 by[4][4];
#pragma unroll
  for (int n4 = 0; n4 < 4; ++n4) {
    const f16x8* yr = (const f16x8*)(Y + ((size_t)b * 4096 + nbase + n4 * 16 + lr) * 128);
#pragma unroll
    for (int ks = 0; ks < 4; ++ks) by[n4][ks] = yr[ks * 4 + lhi];
  }
#pragma unroll
  for (int ot = 0; ot < 4; ++ot) {
    int o0 = w * 64 + ot * 16;
    const f16x8* wr = (const f16x8*)(Wepi + (size_t)(o0 + lr) * 128);
    f16x8 a[4];
#pragma unroll
    for (int ks = 0; ks < 4; ++ks) a[ks] = wr[ks * 4 + lhi];
#pragma unroll
    for (int n4 = 0; n4 < 4; ++n4) {
      f32x4 acc = {0.f, 0.f, 0.f, 0.f};
#pragma unroll
      for (int ks = 0; ks < 4; ++ks) acc = MFMA16(a[ks], by[n4][ks], acc);
#pragma unroll
      for (int r = 0; r < 4; ++r) {
        int o = o0 + lhi * 4 + r;
        int n = nbase + n4 * 16 + lr;
        size_t idx = ((size_t)b * 256 + o) * 4096 + n;
        out[idx] = x[idx] + Wb[o] + acc[r];
      }
    }
  }
}

extern "C" void kernel_launch(void* const* d_in, const int* in_sizes, int n_in,
                              void* d_out, int out_size, void* d_ws, size_t ws_size,
                              hipStream_t stream) {
  const float* x       = (const float*)d_in[0];
  const float* g_w     = (const float*)d_in[1];
  const float* g_b     = (const float*)d_in[2];
  const float* theta_w = (const float*)d_in[3];
  const float* theta_b = (const float*)d_in[4];
  const float* phi_w   = (const float*)d_in[5];
  const float* phi_b   = (const float*)d_in[6];
  const float* W_w     = (const float*)d_in[7];
  const float* W_b     = (const float*)d_in[8];
  float* out = (float*)d_out;

  f16* xT   = (f16*)d_ws;                       // [8,4096,256] 16MB; reused as Yp
  f16* Q    = xT + (size_t)8 * 4096 * 256;      // [8,4096,128] 8MB; reused as Y
  f16* Kk   = Q + (size_t)8 * 4096 * 128;       // 8MB
  f16* Vt   = Kk + (size_t)8 * 4096 * 128;      // 8MB
  f16* Wall = Vt + (size_t)8 * 4096 * 128;      // [384,256]
  f16* Wepi = Wall + 384 * 256;                 // [256,128]
  float2* ml = (float2*)(Wepi + 256 * 128);     // [2][8][4096]
  f16* Yp   = xT;                               // [2][8*4096][128] = 16MB
  f16* Y    = Q;                                // final attention output

  wcvt_k<<<512, 256, 0, stream>>>(theta_w, phi_w, g_w, W_w, Wall, Wepi);
  xpose_k<<<2048, 256, 0, stream>>>(x, xT);
  proj_k<<<512, 256, 0, stream>>>(xT, Wall, theta_b, phi_b, g_b, Q, Kk, Vt);
  attn_k<<<512, 256, 0, stream>>>(Q, Kk, Vt, Yp, ml);
  comb_k<<<2048, 256, 0, stream>>>(Yp, ml, Y);
  epi_k<<<512, 256, 0, stream>>>(Y, Wepi, W_b, x, out);
}